// Round 8
// baseline (4687.421 us; speedup 1.0000x reference)
//
#include <hip/hip_runtime.h>
#include <math.h>

// Unfused mul/add EVERYWHERE (file scope): the exact-chain replication of
// numpy's einsum requires separately-rounded mul and add.
#pragma clang fp contract(off)

// MoE gate: logits = x @ W^T + bias ; softmax ; top-8 ; dense scatter.
// Outputs (float32): vals[16384*8] | idx[16384*8] | dense[16384*64].
//
// PASSED math (r3/r5/r6) — DO NOT CHANGE: logits replicate numpy's einsum
// inner loop (npyv SSE2/SSE3, no FMA): 16-element blocks ascending, REVERSE
// vector order within block, every mul/add separately rounded, final SSE3
// hadd tree (L0+L1)+(L2+L3). Top-8 ranked by these exact f32 logits,
// strict >, lowest index on tie; softmax = exp(l-max), np pairwise-8 sum,
// IEEE div.
//
// r8 = r7 with the AS1 deref done via clang ext_vector (builtin type: no
// HIP_vector_type operator= that can't bind an AS1 reference). W loads are
// global_load_dwordx4 on vmcnt (in-order, counted); lgkm carries only the
// in-order ds_reads of x. This unmixes the counters so the compiler can
// software-pipeline both streams (r5/r6 stalled ~65% on s_load lgkmcnt(0)
// drains).

#define NROWS 16384
#define DIM   2048
#define NE    64
#define DC    64
#define NTILES (DIM / DC)   // 32

typedef float vf4 __attribute__((ext_vector_type(4)));
typedef const __attribute__((address_space(1))) float gfloat;
typedef const __attribute__((address_space(1))) vf4   gvf4;

__device__ __forceinline__ void ld16_lds(const float* g, void* l) {
  __builtin_amdgcn_global_load_lds((const __attribute__((address_space(1))) void*)g,
                                   (__attribute__((address_space(3))) void*)l, 16, 0, 0);
}

// np 16-element block, reverse order, unfused mul/add.
#define NP_BLOCK(A, Q0, Q1, Q2, Q3, R0, R1, R2, R3) \
  A.x = A.x + Q3.x * R3.x;  A.y = A.y + Q3.y * R3.y; \
  A.z = A.z + Q3.z * R3.z;  A.w = A.w + Q3.w * R3.w; \
  A.x = A.x + Q2.x * R2.x;  A.y = A.y + Q2.y * R2.y; \
  A.z = A.z + Q2.z * R2.z;  A.w = A.w + Q2.w * R2.w; \
  A.x = A.x + Q1.x * R1.x;  A.y = A.y + Q1.y * R1.y; \
  A.z = A.z + Q1.z * R1.z;  A.w = A.w + Q1.w * R1.w; \
  A.x = A.x + Q0.x * R0.x;  A.y = A.y + Q0.y * R0.y; \
  A.z = A.z + Q0.z * R0.z;  A.w = A.w + Q0.w * R0.w;

__global__ __launch_bounds__(256, 4)
void logits_kernel(const float* __restrict__ x, const float* __restrict__ w,
                   const float* __restrict__ bias, float* __restrict__ lg)
{
  __shared__ float4 xs[2][64 * (DC / 4)];   // 2 x 16 KB

  const int t    = threadIdx.x;
  const int wv   = t >> 6;      // 0..3 -> expert quad within group
  const int lane = t & 63;      // row within tile
  // XCD decode: 4 sibling blocks (same 64 rows, expert groups 0..3) share an
  // XCD so the x-tile is fetched once per XCD L2 (default assignment = bid&7).
  const int bid = blockIdx.x;          // 0..1023
  const int ix  = bid >> 3;            // 0..127
  const int qg  = ix & 3;              // expert group
  const int rg  = (bid & 7) + ((ix >> 2) << 3);  // row group 0..255 (bijective)
  const int rowBase = rg << 6;
  const int e_base  = __builtin_amdgcn_readfirstlane((qg << 4) | (wv << 2));

  // W base in explicit global AS, laundered so the compiler can't prove it
  // uniform: loads become global_load_dwordx4 (vmcnt-only; NOT s_load on
  // lgkm, NOT flat_load which would bump both counters).
  gfloat* wg = (gfloat*)(w + (size_t)e_base * DIM);
  asm volatile("" : "+v"(wg));

  auto stage = [&](int buf, int kt) {
    const int d0 = kt * DC;
#pragma unroll
    for (int it = 0; it < 4; ++it) {
      int q   = (it << 8) + t;     // float4 index in [64][16] tile
      int row = q >> 4;
      int sp  = q & 15;
      int ss  = sp ^ (row & 7);    // swizzle on the GLOBAL source (involution)
      const float* g = x + (size_t)(rowBase + row) * DIM + d0 + (ss << 2);
      ld16_lds(g, &xs[buf][q]);
    }
  };

  float4 acc[4];
#pragma unroll
  for (int e = 0; e < 4; ++e) acc[e] = make_float4(0.f, 0.f, 0.f, 0.f);

  // W load for flattened step K (b = K>>2, e = K&3) into rotating slot K&3.
  // All indices compile-time constants after full unroll; per-expert base
  // pointers keep the byte offset (0..60 floats = 0..240 B) in the 13-bit imm.
#define LOADW(K) do {                                              \
    const int _b = (K) >> 2, _e = (K) & 3;                         \
    gfloat* _p = wp_[_e] + (_b << 4);                              \
    wsl[(K) & 3][0] = *(gvf4*)(_p);                                \
    wsl[(K) & 3][1] = *(gvf4*)(_p + 4);                            \
    wsl[(K) & 3][2] = *(gvf4*)(_p + 8);                            \
    wsl[(K) & 3][3] = *(gvf4*)(_p + 12);                           \
  } while (0)

  auto compute = [&](int buf, int kt) {
    gfloat* wt = wg + kt * DC;
    gfloat* wp_[4] = { wt, wt + DIM, wt + 2 * DIM, wt + 3 * DIM };
    const float4* xr = &xs[buf][lane << 4];
    const int sw = lane & 7;
    // x tile reads: lgkm carries ONLY these in-order ds_reads now -> the
    // compiler can use counted lgkmcnt and pipeline them.
    float4 q[4][4];
#pragma unroll
    for (int b = 0; b < 4; ++b)
#pragma unroll
      for (int j = 0; j < 4; ++j) q[b][j] = xr[(4 * b + j) ^ sw];

    vf4 wsl[4][4];
    LOADW(0); LOADW(1); LOADW(2);          // prime 3 slots (vmcnt)
#pragma unroll
    for (int i = 0; i < 16; ++i) {         // i = b*4 + e; b outer asc, e inner
      if (i + 3 < 16) LOADW(i + 3);        // prefetch distance 3
      const int b = i >> 2, e = i & 3;
      NP_BLOCK(acc[e], q[b][0], q[b][1], q[b][2], q[b][3],
               wsl[i & 3][0], wsl[i & 3][1], wsl[i & 3][2], wsl[i & 3][3]);
    }
  };

  stage(0, 0);
#pragma unroll 1
  for (int kt = 0; kt < NTILES - 1; ++kt) {
    stage((kt + 1) & 1, kt + 1);                       // prefetch next tile
    // conservative-correct: stage(cur) is the OLDEST outstanding VMEM op;
    // waiting to <=4 outstanding guarantees it landed (W tails drained by
    // their consuming NP_BLOCKs inside compute).
    asm volatile("s_waitcnt vmcnt(4)" ::: "memory");
    __builtin_amdgcn_s_barrier();
    compute(kt & 1, kt);
    __builtin_amdgcn_s_barrier();                      // readers done
    asm volatile("" ::: "memory");
  }
  asm volatile("s_waitcnt vmcnt(0)" ::: "memory");
  __builtin_amdgcn_s_barrier();
  compute((NTILES - 1) & 1, NTILES - 1);

  {
    float4 res;
    float s01, s23;
    s01 = acc[0].x + acc[0].y; s23 = acc[0].z + acc[0].w;
    res.x = (s01 + s23) + bias[e_base + 0];
    s01 = acc[1].x + acc[1].y; s23 = acc[1].z + acc[1].w;
    res.y = (s01 + s23) + bias[e_base + 1];
    s01 = acc[2].x + acc[2].y; s23 = acc[2].z + acc[2].w;
    res.z = (s01 + s23) + bias[e_base + 2];
    s01 = acc[3].x + acc[3].y; s23 = acc[3].z + acc[3].w;
    res.w = (s01 + s23) + bias[e_base + 3];
    *(float4*)(lg + (size_t)(rowBase + lane) * NE + e_base) = res;
  }
}

// B: per-row softmax + top-8 + dense scatter, logits read+overwritten in place.
__global__ __launch_bounds__(256, 1)
void finish_kernel(float* __restrict__ gate, float* __restrict__ out_vals,
                   float* __restrict__ out_idx)
{
  const int r = blockIdx.x * 256 + threadIdx.x;
  float l[NE], p[NE];
  {
    const float4* gp = (const float4*)(gate + (size_t)r * NE);
    float4* lp = (float4*)l;
#pragma unroll
    for (int i = 0; i < 16; ++i) lp[i] = gp[i];
  }
  float m = l[0];
#pragma unroll
  for (int e = 1; e < NE; ++e) m = fmaxf(m, l[e]);
#pragma unroll
  for (int e = 0; e < NE; ++e) p[e] = expf(l[e] - m);
  float rs[8];
#pragma unroll
  for (int j = 0; j < 8; ++j) rs[j] = p[j];
#pragma unroll
  for (int i = 8; i < NE; i += 8)
#pragma unroll
    for (int j = 0; j < 8; ++j) rs[j] = rs[j] + p[i + j];
  float s = ((rs[0] + rs[1]) + (rs[2] + rs[3])) + ((rs[4] + rs[5]) + (rs[6] + rs[7]));
#pragma unroll
  for (int e = 0; e < NE; ++e) p[e] = p[e] / s;

  // top-8 ranked by exact logits (r3-passed semantics): strict >, low idx tie.
  unsigned long long used = 0;
#pragma unroll
  for (int k = 0; k < 8; ++k) {
    float best = -INFINITY; int bi = 0;
#pragma unroll
    for (int e = 0; e < NE; ++e) {
      bool ok = (((used >> e) & 1ull) == 0ull) && (l[e] > best);
      best = ok ? l[e] : best;
      bi   = ok ? e    : bi;
    }
    used |= 1ull << bi;
    out_vals[(size_t)r * 8 + k] = p[bi];
    out_idx [(size_t)r * 8 + k] = (float)bi;
  }

  {
    float4* gp = (float4*)(gate + (size_t)r * NE);
#pragma unroll
    for (int i = 0; i < 16; ++i) {
      int e = i << 2;
      float4 v;
      v.x = ((used >> (e + 0)) & 1ull) ? p[e + 0] : 0.0f;
      v.y = ((used >> (e + 1)) & 1ull) ? p[e + 1] : 0.0f;
      v.z = ((used >> (e + 2)) & 1ull) ? p[e + 2] : 0.0f;
      v.w = ((used >> (e + 3)) & 1ull) ? p[e + 3] : 0.0f;
      gp[i] = v;
    }
  }
}

extern "C" void kernel_launch(void* const* d_in, const int* in_sizes, int n_in,
                              void* d_out, int out_size, void* d_ws, size_t ws_size,
                              hipStream_t stream) {
  const float* x    = (const float*)d_in[0];
  const float* w    = (const float*)d_in[1];
  const float* bias = (const float*)d_in[2];
  float* out   = (float*)d_out;
  float* vals  = out;                       // 16384*8
  float* idx   = out + (size_t)NROWS * 8;   // 16384*8
  float* dense = out + (size_t)NROWS * 16;  // 16384*64 (A's logit scratch)
  (void)in_sizes; (void)n_in; (void)out_size; (void)d_ws; (void)ws_size;
  logits_kernel<<<dim3(1024), dim3(256), 0, stream>>>(x, w, bias, dense);
  finish_kernel<<<dim3(NROWS / 256), dim3(256), 0, stream>>>(dense, vals, idx);
}

// Round 9
// 156.390 us; speedup vs baseline: 29.9727x; 29.9727x over previous
//
#include <hip/hip_runtime.h>
#include <math.h>

// Unfused mul/add EVERYWHERE (file scope): the exact-chain replication of
// numpy's einsum requires separately-rounded mul and add. Packed
// v_pk_mul_f32/v_pk_add_f32 are two independent IEEE-rounded ops per instr —
// allowed; fusion (fma) is not.
#pragma clang fp contract(off)

// MoE gate: logits = x @ W^T + bias ; softmax ; top-8 ; dense scatter.
// Outputs (float32): vals[16384*8] | idx[16384*8] | dense[16384*64].
//
// PASSED math (r3/r5/r6) — DO NOT CHANGE (bit-exact np replication):
// np-einsum inner loop (npyv SSE2/SSE3, no FMA): 4 partial np-lanes (k mod 4),
// 16-element blocks ascending, REVERSE vector order within block, every
// mul/add separately rounded, final SSE3 hadd tree (L0+L1)+(L2+L3). Top-8
// ranked by these exact f32 logits, strict >, lowest index on tie; softmax =
// exp(l-max), np pairwise-8 sum, IEEE div.
//
// r9: revert r8's pointer launder (it forced per-lane W pointers + VGPR
// pressure the allocator answered with 9.5 GB of scratch spill). Back to
// r5's s_load-W / LDS-x structure at low register pressure, but with the
// np-lanes PAIRED into <2 x float> so the math lowers to packed
// v_pk_mul_f32/v_pk_add_f32: 16 VALU instrs per 16-block instead of 32.
// acc01 = (L0,L1), acc23 = (L2,L3); per-element chains unchanged.

#define NROWS 16384
#define DIM   2048
#define NE    64
#define DC    64
#define NTILES (DIM / DC)   // 32

typedef float vf2 __attribute__((ext_vector_type(2)));
typedef float vf4 __attribute__((ext_vector_type(4)));

__device__ __forceinline__ void ld16_lds(const float* g, void* l) {
  __builtin_amdgcn_global_load_lds((const __attribute__((address_space(1))) void*)g,
                                   (__attribute__((address_space(3))) void*)l, 16, 0, 0);
}

__global__ __launch_bounds__(256, 4)
void logits_kernel(const float* __restrict__ x, const float* __restrict__ w,
                   const float* __restrict__ bias, float* __restrict__ lg)
{
  __shared__ vf4 xs[2][64 * (DC / 4)];   // 2 x 16 KB

  const int t    = threadIdx.x;
  const int wv   = t >> 6;      // 0..3 -> expert quad within group
  const int lane = t & 63;      // row within tile
  // XCD decode: 4 sibling blocks (same 64 rows, expert groups 0..3) share an
  // XCD so the x-tile is fetched once per XCD L2 (default assignment = bid&7).
  const int bid = blockIdx.x;          // 0..1023
  const int ix  = bid >> 3;            // 0..127
  const int qg  = ix & 3;              // expert group
  const int rg  = (bid & 7) + ((ix >> 2) << 3);  // row group 0..255 (bijective)
  const int rowBase = rg << 6;
  const int e_base  = __builtin_amdgcn_readfirstlane((qg << 4) | (wv << 2));
  const float* wb = w + (size_t)e_base * DIM;   // wave-uniform -> s_load path

  auto stage = [&](int buf, int kt) {
    const int d0 = kt * DC;
#pragma unroll
    for (int it = 0; it < 4; ++it) {
      int q   = (it << 8) + t;     // vf4 index in [64][16] tile
      int row = q >> 4;
      int sp  = q & 15;
      int ss  = sp ^ (row & 7);    // swizzle on the GLOBAL source (involution)
      const float* g = x + (size_t)(rowBase + row) * DIM + d0 + (ss << 2);
      ld16_lds(g, &xs[buf][q]);
    }
  };

  // acc01[e] = np-lanes (L0,L1); acc23[e] = (L2,L3).
  vf2 acc01[4], acc23[4];
#pragma unroll
  for (int e = 0; e < 4; ++e) { acc01[e] = (vf2)(0.f); acc23[e] = (vf2)(0.f); }

  auto compute = [&](int buf, int kt) {
    const int d0 = kt * DC;
    const vf4* xr = &xs[buf][lane << 4];
    const int sw = lane & 7;
#pragma unroll
    for (int b = 0; b < 4; ++b) {        // np 16-blocks, ascending
      vf4 q0 = xr[(4 * b + 0) ^ sw];
      vf4 q1 = xr[(4 * b + 1) ^ sw];
      vf4 q2 = xr[(4 * b + 2) ^ sw];
      vf4 q3 = xr[(4 * b + 3) ^ sw];
      const float* wp = wb + d0 + (b << 4);
#pragma unroll
      for (int e = 0; e < 4; ++e) {
        const vf4* we = (const vf4*)(wp + (size_t)e * DIM);  // uniform -> s_load
        vf4 r0 = we[0], r1 = we[1], r2 = we[2], r3 = we[3];
        // np chain, reverse vector order (j=3,2,1,0), mul/add separately
        // rounded; .xy -> acc01 (elements 4j,4j+1), .zw -> acc23 (4j+2,4j+3).
        acc01[e] = acc01[e] + q3.xy * r3.xy;
        acc23[e] = acc23[e] + q3.zw * r3.zw;
        acc01[e] = acc01[e] + q2.xy * r2.xy;
        acc23[e] = acc23[e] + q2.zw * r2.zw;
        acc01[e] = acc01[e] + q1.xy * r1.xy;
        acc23[e] = acc23[e] + q1.zw * r1.zw;
        acc01[e] = acc01[e] + q0.xy * r0.xy;
        acc23[e] = acc23[e] + q0.zw * r0.zw;
      }
    }
  };

  stage(0, 0);
#pragma unroll 1
  for (int kt = 0; kt < NTILES - 1; ++kt) {
    stage((kt + 1) & 1, kt + 1);                       // prefetch next tile
    asm volatile("s_waitcnt vmcnt(4)" ::: "memory");   // cur tile staged
    __builtin_amdgcn_s_barrier();
    compute(kt & 1, kt);
    __builtin_amdgcn_s_barrier();                      // readers done
    asm volatile("" ::: "memory");
  }
  asm volatile("s_waitcnt vmcnt(0)" ::: "memory");
  __builtin_amdgcn_s_barrier();
  compute((NTILES - 1) & 1, NTILES - 1);

  {
    // SSE3 hadd tree per expert: (L0+L1)+(L2+L3), then +bias (zeros).
    float4 res;
    float s01, s23;
    s01 = acc01[0].x + acc01[0].y; s23 = acc23[0].x + acc23[0].y;
    res.x = (s01 + s23) + bias[e_base + 0];
    s01 = acc01[1].x + acc01[1].y; s23 = acc23[1].x + acc23[1].y;
    res.y = (s01 + s23) + bias[e_base + 1];
    s01 = acc01[2].x + acc01[2].y; s23 = acc23[2].x + acc23[2].y;
    res.z = (s01 + s23) + bias[e_base + 2];
    s01 = acc01[3].x + acc01[3].y; s23 = acc23[3].x + acc23[3].y;
    res.w = (s01 + s23) + bias[e_base + 3];
    *(float4*)(lg + (size_t)(rowBase + lane) * NE + e_base) = res;
  }
}

// B: per-row softmax + top-8 + dense scatter, logits read+overwritten in place.
__global__ __launch_bounds__(256, 1)
void finish_kernel(float* __restrict__ gate, float* __restrict__ out_vals,
                   float* __restrict__ out_idx)
{
  const int r = blockIdx.x * 256 + threadIdx.x;
  float l[NE], p[NE];
  {
    const float4* gp = (const float4*)(gate + (size_t)r * NE);
    float4* lp = (float4*)l;
#pragma unroll
    for (int i = 0; i < 16; ++i) lp[i] = gp[i];
  }
  float m = l[0];
#pragma unroll
  for (int e = 1; e < NE; ++e) m = fmaxf(m, l[e]);
#pragma unroll
  for (int e = 0; e < NE; ++e) p[e] = expf(l[e] - m);
  float rs[8];
#pragma unroll
  for (int j = 0; j < 8; ++j) rs[j] = p[j];
#pragma unroll
  for (int i = 8; i < NE; i += 8)
#pragma unroll
    for (int j = 0; j < 8; ++j) rs[j] = rs[j] + p[i + j];
  float s = ((rs[0] + rs[1]) + (rs[2] + rs[3])) + ((rs[4] + rs[5]) + (rs[6] + rs[7]));
#pragma unroll
  for (int e = 0; e < NE; ++e) p[e] = p[e] / s;

  // top-8 ranked by exact logits (r3-passed semantics): strict >, low idx tie.
  unsigned long long used = 0;
#pragma unroll
  for (int k = 0; k < 8; ++k) {
    float best = -INFINITY; int bi = 0;
#pragma unroll
    for (int e = 0; e < NE; ++e) {
      bool ok = (((used >> e) & 1ull) == 0ull) && (l[e] > best);
      best = ok ? l[e] : best;
      bi   = ok ? e    : bi;
    }
    used |= 1ull << bi;
    out_vals[(size_t)r * 8 + k] = p[bi];
    out_idx [(size_t)r * 8 + k] = (float)bi;
  }

  {
    float4* gp = (float4*)(gate + (size_t)r * NE);
#pragma unroll
    for (int i = 0; i < 16; ++i) {
      int e = i << 2;
      float4 v;
      v.x = ((used >> (e + 0)) & 1ull) ? p[e + 0] : 0.0f;
      v.y = ((used >> (e + 1)) & 1ull) ? p[e + 1] : 0.0f;
      v.z = ((used >> (e + 2)) & 1ull) ? p[e + 2] : 0.0f;
      v.w = ((used >> (e + 3)) & 1ull) ? p[e + 3] : 0.0f;
      gp[i] = v;
    }
  }
}

extern "C" void kernel_launch(void* const* d_in, const int* in_sizes, int n_in,
                              void* d_out, int out_size, void* d_ws, size_t ws_size,
                              hipStream_t stream) {
  const float* x    = (const float*)d_in[0];
  const float* w    = (const float*)d_in[1];
  const float* bias = (const float*)d_in[2];
  float* out   = (float*)d_out;
  float* vals  = out;                       // 16384*8
  float* idx   = out + (size_t)NROWS * 8;   // 16384*8
  float* dense = out + (size_t)NROWS * 16;  // 16384*64 (A's logit scratch)
  (void)in_sizes; (void)n_in; (void)out_size; (void)d_ws; (void)ws_size;
  logits_kernel<<<dim3(1024), dim3(256), 0, stream>>>(x, w, bias, dense);
  finish_kernel<<<dim3(NROWS / 256), dim3(256), 0, stream>>>(dense, vals, idx);
}

// Round 10
// 134.606 us; speedup vs baseline: 34.8233x; 1.1618x over previous
//
#include <hip/hip_runtime.h>
#include <math.h>

// Unfused mul/add EVERYWHERE (file scope): the exact-chain replication of
// numpy's einsum requires separately-rounded mul and add. Packed
// v_pk_mul_f32/v_pk_add_f32 are two independent IEEE-rounded ops per instr —
// allowed; fusion (fma) is not.
#pragma clang fp contract(off)

// MoE gate: logits = x @ W^T + bias ; softmax ; top-8 ; dense scatter.
// Outputs (float32): vals[16384*8] | idx[16384*8] | dense[16384*64].
//
// PASSED math (r3/r5/r6/r9) — DO NOT CHANGE (bit-exact np replication):
// np-einsum inner loop (npyv SSE2/SSE3, no FMA): 4 partial np-lanes (k mod 4),
// 16-element blocks ascending, REVERSE vector order within block, every
// mul/add separately rounded, final SSE3 hadd tree (L0+L1)+(L2+L3). Top-8
// ranked by these exact f32 logits, strict >, lowest index on tie; softmax =
// exp(l-max), np pairwise-8 sum, IEEE div.
//
// r10: W staged through LDS (4 KB per K-tile for the block's 16 experts) so
// the inner loop has ZERO SMEM: both operands come from in-order ds_read_b128
// on lgkm, which the compiler pipelines with counted lgkmcnt. r9 was
// latency-bound (VALUBusy 26%) on lgkmcnt(0) drains forced by out-of-order
// s_loads of W sharing the counter with x ds_reads. W ds_reads here are
// wave-uniform -> broadcast, conflict-free. LDS 40 KB/block = 4 blocks/CU.

#define NROWS 16384
#define DIM   2048
#define NE    64
#define DC    64
#define NTILES (DIM / DC)   // 32

typedef float vf2 __attribute__((ext_vector_type(2)));
typedef float vf4 __attribute__((ext_vector_type(4)));

__device__ __forceinline__ void ld16_lds(const float* g, void* l) {
  __builtin_amdgcn_global_load_lds((const __attribute__((address_space(1))) void*)g,
                                   (__attribute__((address_space(3))) void*)l, 16, 0, 0);
}

__global__ __launch_bounds__(256, 4)
void logits_kernel(const float* __restrict__ x, const float* __restrict__ w,
                   const float* __restrict__ bias, float* __restrict__ lg)
{
  __shared__ vf4 xs[2][64 * (DC / 4)];   // x: 2 x 16 KB
  __shared__ vf4 ws[2][16 * (DC / 4)];   // W: 2 x 4 KB ([16 experts][16 vf4])

  const int t    = threadIdx.x;
  const int wv   = t >> 6;      // 0..3 -> expert quad within group
  const int lane = t & 63;      // row within tile
  // XCD decode: 4 sibling blocks (same 64 rows, expert groups 0..3) share an
  // XCD so the x-tile is fetched once per XCD L2 (default assignment = bid&7).
  const int bid = blockIdx.x;          // 0..1023
  const int ix  = bid >> 3;            // 0..127
  const int qg  = ix & 3;              // expert group
  const int rg  = (bid & 7) + ((ix >> 2) << 3);  // row group 0..255 (bijective)
  const int rowBase = rg << 6;
  const int e_base  = __builtin_amdgcn_readfirstlane((qg << 4) | (wv << 2));

  auto stage = [&](int buf, int kt) {
    const int d0 = kt * DC;
#pragma unroll
    for (int it = 0; it < 4; ++it) {
      int q   = (it << 8) + t;     // vf4 index in [64][16] x-tile
      int row = q >> 4;
      int sp  = q & 15;
      int ss  = sp ^ (row & 7);    // swizzle on the GLOBAL source (involution)
      const float* g = x + (size_t)(rowBase + row) * DIM + d0 + (ss << 2);
      ld16_lds(g, &xs[buf][q]);
    }
    {
      // W tile: block's 16 experts x 64 floats = 256 vf4; 1 load/thread.
      int le = t >> 4, slot = t & 15;  // local expert, vf4 slot (no swizzle:
                                       // compute reads are uniform/broadcast)
      const float* g = w + (size_t)(qg * 16 + le) * DIM + d0 + (slot << 2);
      ld16_lds(g, &ws[buf][t]);
    }
  };

  // acc01[e] = np-lanes (L0,L1); acc23[e] = (L2,L3).
  vf2 acc01[4], acc23[4];
#pragma unroll
  for (int e = 0; e < 4; ++e) { acc01[e] = (vf2)(0.f); acc23[e] = (vf2)(0.f); }

  auto compute = [&](int buf, int kt) {
    const vf4* xr = &xs[buf][lane << 4];
    const vf4* wr = &ws[buf][(wv << 2) << 4];   // wave's 4 experts
    const int sw = lane & 7;
#pragma unroll
    for (int b = 0; b < 4; ++b) {        // np 16-blocks, ascending
      vf4 q0 = xr[(4 * b + 0) ^ sw];
      vf4 q1 = xr[(4 * b + 1) ^ sw];
      vf4 q2 = xr[(4 * b + 2) ^ sw];
      vf4 q3 = xr[(4 * b + 3) ^ sw];
#pragma unroll
      for (int e = 0; e < 4; ++e) {
        const vf4* we = wr + (e << 4) + (b << 2);  // uniform addr -> broadcast
        vf4 r0 = we[0], r1 = we[1], r2 = we[2], r3 = we[3];
        // np chain, reverse vector order (j=3,2,1,0), mul/add separately
        // rounded; .xy -> acc01 (elements 4j,4j+1), .zw -> acc23 (4j+2,4j+3).
        acc01[e] = acc01[e] + q3.xy * r3.xy;
        acc23[e] = acc23[e] + q3.zw * r3.zw;
        acc01[e] = acc01[e] + q2.xy * r2.xy;
        acc23[e] = acc23[e] + q2.zw * r2.zw;
        acc01[e] = acc01[e] + q1.xy * r1.xy;
        acc23[e] = acc23[e] + q1.zw * r1.zw;
        acc01[e] = acc01[e] + q0.xy * r0.xy;
        acc23[e] = acc23[e] + q0.zw * r0.zw;
      }
    }
  };

  stage(0, 0);
#pragma unroll 1
  for (int kt = 0; kt < NTILES - 1; ++kt) {
    stage((kt + 1) & 1, kt + 1);                       // prefetch next tile (5 loads)
    asm volatile("s_waitcnt vmcnt(5)" ::: "memory");   // cur tile's 5 loads done
    __builtin_amdgcn_s_barrier();
    compute(kt & 1, kt);
    __builtin_amdgcn_s_barrier();                      // readers done
    asm volatile("" ::: "memory");
  }
  asm volatile("s_waitcnt vmcnt(0)" ::: "memory");
  __builtin_amdgcn_s_barrier();
  compute((NTILES - 1) & 1, NTILES - 1);

  {
    // SSE3 hadd tree per expert: (L0+L1)+(L2+L3), then +bias (zeros).
    float4 res;
    float s01, s23;
    s01 = acc01[0].x + acc01[0].y; s23 = acc23[0].x + acc23[0].y;
    res.x = (s01 + s23) + bias[e_base + 0];
    s01 = acc01[1].x + acc01[1].y; s23 = acc23[1].x + acc23[1].y;
    res.y = (s01 + s23) + bias[e_base + 1];
    s01 = acc01[2].x + acc01[2].y; s23 = acc23[2].x + acc23[2].y;
    res.z = (s01 + s23) + bias[e_base + 2];
    s01 = acc01[3].x + acc01[3].y; s23 = acc23[3].x + acc23[3].y;
    res.w = (s01 + s23) + bias[e_base + 3];
    *(float4*)(lg + (size_t)(rowBase + lane) * NE + e_base) = res;
  }
}

// B: per-row softmax + top-8 + dense scatter, logits read+overwritten in place.
__global__ __launch_bounds__(256, 1)
void finish_kernel(float* __restrict__ gate, float* __restrict__ out_vals,
                   float* __restrict__ out_idx)
{
  const int r = blockIdx.x * 256 + threadIdx.x;
  float l[NE], p[NE];
  {
    const float4* gp = (const float4*)(gate + (size_t)r * NE);
    float4* lp = (float4*)l;
#pragma unroll
    for (int i = 0; i < 16; ++i) lp[i] = gp[i];
  }
  float m = l[0];
#pragma unroll
  for (int e = 1; e < NE; ++e) m = fmaxf(m, l[e]);
#pragma unroll
  for (int e = 0; e < NE; ++e) p[e] = expf(l[e] - m);
  float rs[8];
#pragma unroll
  for (int j = 0; j < 8; ++j) rs[j] = p[j];
#pragma unroll
  for (int i = 8; i < NE; i += 8)
#pragma unroll
    for (int j = 0; j < 8; ++j) rs[j] = rs[j] + p[i + j];
  float s = ((rs[0] + rs[1]) + (rs[2] + rs[3])) + ((rs[4] + rs[5]) + (rs[6] + rs[7]));
#pragma unroll
  for (int e = 0; e < NE; ++e) p[e] = p[e] / s;

  // top-8 ranked by exact logits (r3-passed semantics): strict >, low idx tie.
  unsigned long long used = 0;
#pragma unroll
  for (int k = 0; k < 8; ++k) {
    float best = -INFINITY; int bi = 0;
#pragma unroll
    for (int e = 0; e < NE; ++e) {
      bool ok = (((used >> e) & 1ull) == 0ull) && (l[e] > best);
      best = ok ? l[e] : best;
      bi   = ok ? e    : bi;
    }
    used |= 1ull << bi;
    out_vals[(size_t)r * 8 + k] = p[bi];
    out_idx [(size_t)r * 8 + k] = (float)bi;
  }

  {
    float4* gp = (float4*)(gate + (size_t)r * NE);
#pragma unroll
    for (int i = 0; i < 16; ++i) {
      int e = i << 2;
      float4 v;
      v.x = ((used >> (e + 0)) & 1ull) ? p[e + 0] : 0.0f;
      v.y = ((used >> (e + 1)) & 1ull) ? p[e + 1] : 0.0f;
      v.z = ((used >> (e + 2)) & 1ull) ? p[e + 2] : 0.0f;
      v.w = ((used >> (e + 3)) & 1ull) ? p[e + 3] : 0.0f;
      gp[i] = v;
    }
  }
}

extern "C" void kernel_launch(void* const* d_in, const int* in_sizes, int n_in,
                              void* d_out, int out_size, void* d_ws, size_t ws_size,
                              hipStream_t stream) {
  const float* x    = (const float*)d_in[0];
  const float* w    = (const float*)d_in[1];
  const float* bias = (const float*)d_in[2];
  float* out   = (float*)d_out;
  float* vals  = out;                       // 16384*8
  float* idx   = out + (size_t)NROWS * 8;   // 16384*8
  float* dense = out + (size_t)NROWS * 16;  // 16384*64 (A's logit scratch)
  (void)in_sizes; (void)n_in; (void)out_size; (void)d_ws; (void)ws_size;
  logits_kernel<<<dim3(1024), dim3(256), 0, stream>>>(x, w, bias, dense);
  finish_kernel<<<dim3(NROWS / 256), dim3(256), 0, stream>>>(dense, vals, idx);
}

// Round 11
// 131.321 us; speedup vs baseline: 35.6944x; 1.0250x over previous
//
#include <hip/hip_runtime.h>
#include <math.h>

// Unfused mul/add EVERYWHERE (file scope): the exact-chain replication of
// numpy's einsum requires separately-rounded mul and add. Packed
// v_pk_mul_f32/v_pk_add_f32 are two independent IEEE-rounded ops per instr —
// allowed; fusion (fma) is not.
#pragma clang fp contract(off)

// MoE gate: logits = x @ W^T + bias ; softmax ; top-8 ; dense scatter.
// Outputs (float32): vals[16384*8] | idx[16384*8] | dense[16384*64].
//
// PASSED math (r3/r5/r6/r9/r10) — DO NOT CHANGE (bit-exact np replication):
// np-einsum inner loop (npyv SSE2/SSE3, no FMA): 4 partial np-lanes (k mod 4),
// 16-element blocks ascending over the full K-walk, REVERSE vector order
// within block, every mul/add separately rounded, final SSE3 hadd tree
// (L0+L1)+(L2+L3). Top-8 ranked by these exact f32 logits, strict >, lowest
// index on tie; softmax = exp(l-max), np pairwise-8 sum, IEEE div.
//
// r11: r10 was LDS-pipe-bound (80 ds_reads vs 128 packed ops per thread-tile;
// W broadcast reads dominate at 1 row/lane). Changes:
//  - 2 rows/lane (tile 128 rows x 16 experts): W-reads per op halved;
//    per thread-tile now 16 x-reads + 32 W-reads vs 128 packed ops.
//  - DC=32, 3 LDS buffers (54 KB), prefetch-1, ONE barrier per tile
//    (buffer distance 2 mod 3 makes stage-vs-lagging-compute safe).
//  - W stage via 2 uniform size-4 global_load_lds per thread (uniform
//    per-wave vmcnt counts -> vmcnt(6) exact).

#define NROWS 16384
#define DIM   2048
#define NE    64
#define DC    32
#define NTILES (DIM / DC)   // 64
#define TROWS 128
#define NBUF  3

typedef float vf2 __attribute__((ext_vector_type(2)));
typedef float vf4 __attribute__((ext_vector_type(4)));

__device__ __forceinline__ void ld16_lds(const float* g, void* l) {
  __builtin_amdgcn_global_load_lds((const __attribute__((address_space(1))) void*)g,
                                   (__attribute__((address_space(3))) void*)l, 16, 0, 0);
}
__device__ __forceinline__ void ld4_lds(const float* g, void* l) {
  __builtin_amdgcn_global_load_lds((const __attribute__((address_space(1))) void*)g,
                                   (__attribute__((address_space(3))) void*)l, 4, 0, 0);
}

__global__ __launch_bounds__(256, 2)
void logits_kernel(const float* __restrict__ x, const float* __restrict__ w,
                   const float* __restrict__ bias, float* __restrict__ lg)
{
  __shared__ vf4 xs[NBUF][TROWS * (DC / 4)];   // 3 x 16 KB
  __shared__ vf4 ws[NBUF][16 * (DC / 4)];      // 3 x 2 KB

  const int t    = threadIdx.x;
  const int wv   = t >> 6;      // 0..3 -> expert quad within group
  const int lane = t & 63;
  // XCD decode: 4 sibling blocks (same 128 rows, expert groups 0..3) share an
  // XCD so the x-tile is fetched once per XCD L2 (default assignment = bid&7).
  const int bid = blockIdx.x;          // 0..511
  const int ix  = bid >> 3;            // 0..63
  const int qg  = ix & 3;              // expert group (16 experts)
  const int rg  = (bid & 7) + ((ix >> 2) << 3);  // row group 0..127 (bijective)
  const int rowBase = rg << 7;         // 128 rows per block
  const int e_base  = __builtin_amdgcn_readfirstlane((qg << 4) | (wv << 2));

  auto stage = [&](int buf, int kt) {
    const int d0 = kt * DC;
#pragma unroll
    for (int it = 0; it < 4; ++it) {
      int q   = (it << 8) + t;     // vf4 index in [128][8] x-tile
      int row = q >> 3;
      int sp  = q & 7;
      int ss  = sp ^ (row & 7);    // swizzle on the GLOBAL source (involution)
      const float* g = x + (size_t)(rowBase + row) * DIM + d0 + (ss << 2);
      ld16_lds(g, &xs[buf][q]);
    }
    // W tile: 16 experts x 32 floats = 512 dwords; 2 uniform size-4 loads per
    // thread, lane-ordered so each wave instr writes 256 contiguous LDS bytes.
#pragma unroll
    for (int j = 0; j < 2; ++j) {
      int m = (wv << 7) + (j << 6) + lane;   // dword idx 0..511
      int e = m >> 5, c = m & 31;
      const float* g = w + (size_t)(qg * 16 + e) * DIM + d0 + c;
      ld4_lds(g, (float*)&ws[buf][0] + m);
    }
  };

  // acc01[r][e] = np-lanes (L0,L1); acc23[r][e] = (L2,L3); r = row slot.
  vf2 acc01[2][4], acc23[2][4];
#pragma unroll
  for (int r = 0; r < 2; ++r)
#pragma unroll
    for (int e = 0; e < 4; ++e) { acc01[r][e] = (vf2)(0.f); acc23[r][e] = (vf2)(0.f); }

  auto compute = [&](int buf) {
    const int sw = lane & 7;     // (lane+64)&7 == lane&7: same swizzle both rows
#pragma unroll
    for (int b = 0; b < 2; ++b) {        // np 16-blocks, ascending
      vf4 q0[2], q1[2], q2[2], q3[2];
#pragma unroll
      for (int r = 0; r < 2; ++r) {
        const vf4* xr = &xs[buf][(lane + (r << 6)) << 3];
        q0[r] = xr[(4 * b + 0) ^ sw];
        q1[r] = xr[(4 * b + 1) ^ sw];
        q2[r] = xr[(4 * b + 2) ^ sw];
        q3[r] = xr[(4 * b + 3) ^ sw];
      }
#pragma unroll
      for (int e = 0; e < 4; ++e) {
        const vf4* we = &ws[buf][(((wv << 2) + e) << 3) + (b << 2)];  // uniform -> broadcast
        vf4 r0 = we[0], r1 = we[1], r2 = we[2], r3 = we[3];
#pragma unroll
        for (int r = 0; r < 2; ++r) {
          // np chain, reverse vector order (j=3,2,1,0), mul/add separately
          // rounded; .xy -> acc01, .zw -> acc23. Chains per (r,e) independent.
          acc01[r][e] = acc01[r][e] + q3[r].xy * r3.xy;
          acc23[r][e] = acc23[r][e] + q3[r].zw * r3.zw;
          acc01[r][e] = acc01[r][e] + q2[r].xy * r2.xy;
          acc23[r][e] = acc23[r][e] + q2[r].zw * r2.zw;
          acc01[r][e] = acc01[r][e] + q1[r].xy * r1.xy;
          acc23[r][e] = acc23[r][e] + q1[r].zw * r1.zw;
          acc01[r][e] = acc01[r][e] + q0[r].xy * r0.xy;
          acc23[r][e] = acc23[r][e] + q0[r].zw * r0.zw;
        }
      }
    }
  };

  // ---- 3-buffer, prefetch-1, ONE barrier per tile ----
  stage(0, 0);
  int sb = 1, cb = 0;
#pragma unroll 1
  for (int kt = 0; kt < NTILES - 1; ++kt) {
    stage(sb, kt + 1);                                 // 6 loads -> buf sb
    asm volatile("s_waitcnt vmcnt(6)" ::: "memory");   // stage(kt) landed
    __builtin_amdgcn_s_barrier();                      // all waves see buf cb
    compute(cb);
    sb = (sb == NBUF - 1) ? 0 : sb + 1;
    cb = (cb == NBUF - 1) ? 0 : cb + 1;
  }
  asm volatile("s_waitcnt vmcnt(0)" ::: "memory");
  __builtin_amdgcn_s_barrier();
  compute(cb);

  {
    // SSE3 hadd tree per (row, expert): (L0+L1)+(L2+L3), then +bias (zeros).
#pragma unroll
    for (int r = 0; r < 2; ++r) {
      float4 res;
      float s01, s23;
      s01 = acc01[r][0].x + acc01[r][0].y; s23 = acc23[r][0].x + acc23[r][0].y;
      res.x = (s01 + s23) + bias[e_base + 0];
      s01 = acc01[r][1].x + acc01[r][1].y; s23 = acc23[r][1].x + acc23[r][1].y;
      res.y = (s01 + s23) + bias[e_base + 1];
      s01 = acc01[r][2].x + acc01[r][2].y; s23 = acc23[r][2].x + acc23[r][2].y;
      res.z = (s01 + s23) + bias[e_base + 2];
      s01 = acc01[r][3].x + acc01[r][3].y; s23 = acc23[r][3].x + acc23[r][3].y;
      res.w = (s01 + s23) + bias[e_base + 3];
      *(float4*)(lg + (size_t)(rowBase + lane + (r << 6)) * NE + e_base) = res;
    }
  }
}

// B: per-row softmax + top-8 + dense scatter, logits read+overwritten in place.
__global__ __launch_bounds__(256, 1)
void finish_kernel(float* __restrict__ gate, float* __restrict__ out_vals,
                   float* __restrict__ out_idx)
{
  const int r = blockIdx.x * 256 + threadIdx.x;
  float l[NE], p[NE];
  {
    const float4* gp = (const float4*)(gate + (size_t)r * NE);
    float4* lp = (float4*)l;
#pragma unroll
    for (int i = 0; i < 16; ++i) lp[i] = gp[i];
  }
  float m = l[0];
#pragma unroll
  for (int e = 1; e < NE; ++e) m = fmaxf(m, l[e]);
#pragma unroll
  for (int e = 0; e < NE; ++e) p[e] = expf(l[e] - m);
  float rs[8];
#pragma unroll
  for (int j = 0; j < 8; ++j) rs[j] = p[j];
#pragma unroll
  for (int i = 8; i < NE; i += 8)
#pragma unroll
    for (int j = 0; j < 8; ++j) rs[j] = rs[j] + p[i + j];
  float s = ((rs[0] + rs[1]) + (rs[2] + rs[3])) + ((rs[4] + rs[5]) + (rs[6] + rs[7]));
#pragma unroll
  for (int e = 0; e < NE; ++e) p[e] = p[e] / s;

  // top-8 ranked by exact logits (r3-passed semantics): strict >, low idx tie.
  unsigned long long used = 0;
#pragma unroll
  for (int k = 0; k < 8; ++k) {
    float best = -INFINITY; int bi = 0;
#pragma unroll
    for (int e = 0; e < NE; ++e) {
      bool ok = (((used >> e) & 1ull) == 0ull) && (l[e] > best);
      best = ok ? l[e] : best;
      bi   = ok ? e    : bi;
    }
    used |= 1ull << bi;
    out_vals[(size_t)r * 8 + k] = p[bi];
    out_idx [(size_t)r * 8 + k] = (float)bi;
  }

  {
    float4* gp = (float4*)(gate + (size_t)r * NE);
#pragma unroll
    for (int i = 0; i < 16; ++i) {
      int e = i << 2;
      float4 v;
      v.x = ((used >> (e + 0)) & 1ull) ? p[e + 0] : 0.0f;
      v.y = ((used >> (e + 1)) & 1ull) ? p[e + 1] : 0.0f;
      v.z = ((used >> (e + 2)) & 1ull) ? p[e + 2] : 0.0f;
      v.w = ((used >> (e + 3)) & 1ull) ? p[e + 3] : 0.0f;
      gp[i] = v;
    }
  }
}

extern "C" void kernel_launch(void* const* d_in, const int* in_sizes, int n_in,
                              void* d_out, int out_size, void* d_ws, size_t ws_size,
                              hipStream_t stream) {
  const float* x    = (const float*)d_in[0];
  const float* w    = (const float*)d_in[1];
  const float* bias = (const float*)d_in[2];
  float* out   = (float*)d_out;
  float* vals  = out;                       // 16384*8
  float* idx   = out + (size_t)NROWS * 8;   // 16384*8
  float* dense = out + (size_t)NROWS * 16;  // 16384*64 (A's logit scratch)
  (void)in_sizes; (void)n_in; (void)out_size; (void)d_ws; (void)ws_size;
  logits_kernel<<<dim3(512), dim3(256), 0, stream>>>(x, w, bias, dense);
  finish_kernel<<<dim3(NROWS / 256), dim3(256), 0, stream>>>(dense, vals, idx);
}